// Round 12
// baseline (309.789 us; speedup 1.0000x reference)
//
#include <hip/hip_runtime.h>
#include <hip/hip_bf16.h>

#define S_LEN 4096
#define EMB   768
#define NH    12
#define DH    64

#define KS_STRIDE 72      // padded (36 dwords % 32 = 4): breaks 16-way conflicts
#define VS_STRIDE 136     // padded (68 dwords % 32 = 4)

// finite sentinel instead of -INFINITY: safe under fast-math builds
#define NEG_BIG (-1e30f)

using bf16x8 = __attribute__((ext_vector_type(8))) short;
using bf16x4 = __attribute__((ext_vector_type(4))) short;
using f32x4  = __attribute__((ext_vector_type(4))) float;

__device__ __forceinline__ short f2bf(float f) {
    __hip_bfloat16 h = __float2bfloat16(f);
    short s; __builtin_memcpy(&s, &h, 2); return s;
}
__device__ __forceinline__ float bf2f(short s) {
    __hip_bfloat16 h; __builtin_memcpy(&h, &s, 2);
    return __bfloat162float(h);
}

// pack two f32 -> two bf16 (round-half-up) in one u32 via v_perm_b32
__device__ __forceinline__ unsigned pack_bf16_rh(float a, float b) {
    unsigned ua, ub;
    __builtin_memcpy(&ua, &a, 4);
    __builtin_memcpy(&ub, &b, 4);
    return __builtin_amdgcn_perm(ub + 0x8000u, ua + 0x8000u, 0x07060302u);
}

// async global->LDS, 16B per lane; lds dest = uniform base + lane*16
__device__ __forceinline__ void gld_lds16(const void* g, void* l) {
    __builtin_amdgcn_global_load_lds(
        (const __attribute__((address_space(1))) unsigned int*)g,
        (__attribute__((address_space(3))) unsigned int*)l, 16, 0, 0);
}

__device__ __forceinline__ void cvt8(const float* s, short* d, int i) {
    const float4 a = ((const float4*)s)[i * 2];
    const float4 b = ((const float4*)s)[i * 2 + 1];
    bf16x8 o;
    o[0] = f2bf(a.x); o[1] = f2bf(a.y); o[2] = f2bf(a.z); o[3] = f2bf(a.w);
    o[4] = f2bf(b.x); o[5] = f2bf(b.y); o[6] = f2bf(b.z); o[7] = f2bf(b.w);
    ((bf16x8*)d)[i] = o;
}

// ---------------------------------------------------------------------------
// Kernel 0a/0b: fp32 -> bf16 converts
// ---------------------------------------------------------------------------
__global__ __launch_bounds__(256) void cvt_bf16(
    const float* __restrict__ s, short* __restrict__ d, int n8)
{
    const int i = blockIdx.x * 256 + threadIdx.x;
    if (i < n8) cvt8(s, d, i);
}

__global__ __launch_bounds__(256) void cvt3_bf16(
    const float* __restrict__ x,  short* __restrict__ xb,  int n8x,
    const float* __restrict__ wq, short* __restrict__ wqb, int n8q,
    const float* __restrict__ wo, short* __restrict__ wob, int n8o)
{
    int i = blockIdx.x * 256 + threadIdx.x;
    if (i < n8x) { cvt8(x, xb, i); return; }
    i -= n8x;
    if (i < n8q) { cvt8(wq, wqb, i); return; }
    i -= n8q;
    if (i < n8o) cvt8(wo, wob, i);
}

// ---------------------------------------------------------------------------
// Kernel 1: QKV projection, bf16 inputs, global_load_lds staging (m97 style).
// ---------------------------------------------------------------------------
__global__ __launch_bounds__(256) void qkv_gemm(
    const short* __restrict__ Xb, const short* __restrict__ Wb,
    const float* __restrict__ Bias,
    short* __restrict__ Qw, short* __restrict__ Kw, short* __restrict__ Vt)
{
    __shared__ __align__(16) short As[128 * 64];
    __shared__ __align__(16) short Bs[128 * 64];

    const int m0 = blockIdx.x * 128;
    const int n0 = blockIdx.y * 128;
    const int t = threadIdx.x;
    const int lane = t & 63, wave = t >> 6;
    const int quad = lane >> 4, l16 = lane & 15;
    const int wm = (wave >> 1) * 64, wn = (wave & 1) * 64;
    const int srow = lane >> 3, scol = (lane & 7) * 8;

    f32x4 acc[4][4] = {};

    for (int k0 = 0; k0 < EMB; k0 += 64) {
        #pragma unroll
        for (int qd = 0; qd < 4; qd++) {
            const int chunk = wave * 4 + qd;
            const int row = chunk * 8 + srow;
            gld_lds16(&Xb[(size_t)(m0 + row) * EMB + k0 + scol], &As[chunk * 512]);
            gld_lds16(&Wb[(size_t)(n0 + row) * EMB + k0 + scol], &Bs[chunk * 512]);
        }
        __syncthreads();

        #pragma unroll
        for (int kb = 0; kb < 2; kb++) {
            bf16x8 af[4], bfr[4];
            #pragma unroll
            for (int i = 0; i < 4; i++)
                af[i] = *(const bf16x8*)&As[(wm + i * 16 + l16) * 64 + kb * 32 + quad * 8];
            #pragma unroll
            for (int j = 0; j < 4; j++)
                bfr[j] = *(const bf16x8*)&Bs[(wn + j * 16 + l16) * 64 + kb * 32 + quad * 8];
            #pragma unroll
            for (int i = 0; i < 4; i++)
                #pragma unroll
                for (int j = 0; j < 4; j++)
                    acc[i][j] = __builtin_amdgcn_mfma_f32_16x16x32_bf16(
                        af[i], bfr[j], acc[i][j], 0, 0, 0);
        }
        __syncthreads();
    }

    #pragma unroll
    for (int j = 0; j < 4; j++) {
        const int n = n0 + wn + j * 16 + l16;
        const float bias = Bias[n];
        const int part = n / EMB;
        const int r768 = n % EMB;
        const int h = r768 >> 6, d = r768 & 63;
        #pragma unroll
        for (int i = 0; i < 4; i++) {
            #pragma unroll
            for (int r = 0; r < 4; r++) {
                const int m = m0 + wm + i * 16 + quad * 4 + r;
                const short o = f2bf(acc[i][j][r] + bias);
                if (part == 0)
                    Qw[((size_t)h * S_LEN + m) * DH + d] = o;
                else if (part == 1)
                    Kw[((size_t)h * S_LEN + m) * DH + d] = o;
                else
                    Vt[((size_t)h * DH + d) * S_LEN + m] = o;
            }
        }
    }
}

// ---------------------------------------------------------------------------
// Kernel 2a: split-K flash partial, 512 threads = 8 waves, q-tile 128.
// R12: same per-wave code as R10/R11 (16 q-rows/wave, 64-VGPR no-spill) but
// 8 waves share each staged K/V tile -> tile-iterations, staging traffic,
// and barriers all HALVE vs q-tile 64. LDS 35 KB -> 4 blocks/CU x 8 waves
// = 32 waves/CU occupancy bound.
// ---------------------------------------------------------------------------
template<int NCH, int CKL2>   // chunk keys = 1<<CKL2; k-iters per chunk
__global__ __launch_bounds__(512) void flash_partial(
    const short* __restrict__ Qw, const short* __restrict__ Kw,
    const short* __restrict__ Vt,
    short* __restrict__ Opart, float* __restrict__ Mpart,
    float* __restrict__ Lpart)
{
    const int qt = blockIdx.x;          // 128-row q tile
    const int h  = blockIdx.y;
    const int kc = blockIdx.z;
    const int q0  = qt * 128;
    const int ks0 = kc << CKL2;
    if (ks0 > q0) return;               // chunk entirely masked
    const int KIT = (1 << CKL2) / 128;
    const int nk = min(KIT, qt - KIT * kc + 1);

    __shared__ __align__(16) short SMEM[128 * KS_STRIDE + 64 * VS_STRIDE]; // 35 KB
    short* Ks = SMEM;                   // [key][d]  stride 72
    short* Vs = SMEM + 128 * KS_STRIDE; // [d][key]  stride 136

    const int t = threadIdx.x;
    const int lane = t & 63, wave = t >> 6;     // wave 0..7
    const int quad = lane >> 4, l16 = lane & 15;
    const int qw0 = q0 + wave * 16;     // wave's 16 q rows

    bf16x8 qf[2];
    #pragma unroll
    for (int kb = 0; kb < 2; kb++)
        qf[kb] = *(const bf16x8*)
            &Qw[((size_t)h * S_LEN + qw0 + l16) * DH + kb * 32 + quad * 8];

    float m_i = NEG_BIG, l_i = 0.f;
    f32x4 o_acc[4] = {};                // d = db*16+quad*4+r, q = l16

    for (int kt = 0; kt < nk; kt++) {
        const int k0 = ks0 + kt * 128;
        __syncthreads();
        #pragma unroll
        for (int c = t; c < 1024; c += 512) {
            const int row = c >> 3, cc = (c & 7) * 8;
            *(bf16x8*)&Ks[row * KS_STRIDE + cc] =
                *(const bf16x8*)&Kw[((size_t)h * S_LEN + k0 + row) * DH + cc];
        }
        #pragma unroll
        for (int c = t; c < 1024; c += 512) {
            const int row = c >> 4, cc = (c & 15) * 8;
            *(bf16x8*)&Vs[row * VS_STRIDE + cc] =
                *(const bf16x8*)&Vt[((size_t)h * DH + row) * S_LEN + k0 + cc];
        }
        __syncthreads();

        const bool maskn = (k0 + 127 > q0 + 127) || (k0 == q0); // diag tile only
        #pragma unroll
        for (int sub = 0; sub < 2; sub++) {
            // wave-uniform skip: all 64 keys of this substep beyond wave's q
            if (maskn && k0 + sub * 64 > qw0 + 15) continue;

            // S^T = K·Q^T over 64 keys: key=quad*4+r (per bb), q=l16
            f32x4 sfT[4] = {};
            #pragma unroll
            for (int bb = 0; bb < 4; bb++) {
                #pragma unroll
                for (int kb = 0; kb < 2; kb++) {
                    const bf16x8 kf = *(const bf16x8*)
                        &Ks[((sub * 4 + bb) * 16 + l16) * KS_STRIDE + kb * 32 + quad * 8];
                    sfT[bb] = __builtin_amdgcn_mfma_f32_16x16x32_bf16(
                        kf, qf[kb], sfT[bb], 0, 0, 0);
                }
            }

            const int qg = qw0 + l16;
            if (maskn) {
                #pragma unroll
                for (int bb = 0; bb < 4; bb++)
                    #pragma unroll
                    for (int r = 0; r < 4; r++)
                        if (k0 + (sub * 4 + bb) * 16 + quad * 4 + r > qg)
                            sfT[bb][r] = NEG_BIG;
            }
            float mx = sfT[0][0];
            #pragma unroll
            for (int bb = 0; bb < 4; bb++)
                #pragma unroll
                for (int r = 0; r < 4; r++) mx = fmaxf(mx, sfT[bb][r]);
            mx = fmaxf(mx, __shfl_xor(mx, 16, 64));
            mx = fmaxf(mx, __shfl_xor(mx, 32, 64));
            const float mnew = fmaxf(m_i, mx);
            const float alpha = __expf(m_i - mnew);
            m_i = mnew;
            float rs = 0.f;
            #pragma unroll
            for (int bb = 0; bb < 4; bb++)
                #pragma unroll
                for (int r = 0; r < 4; r++) {
                    const float p = __expf(sfT[bb][r] - mnew);
                    sfT[bb][r] = p;
                    rs += p;
                }
            rs += __shfl_xor(rs, 16, 64);
            rs += __shfl_xor(rs, 32, 64);
            l_i = l_i * alpha + rs;
            #pragma unroll
            for (int db = 0; db < 4; db++) o_acc[db] *= alpha;

            // O^T += V^T·P^T, 16 keys per step, zero-padded K=32 MFMA.
            #pragma unroll
            for (int bb = 0; bb < 4; bb++) {
                int4 pv;
                pv.x = (int)pack_bf16_rh(sfT[bb][0], sfT[bb][1]);
                pv.y = (int)pack_bf16_rh(sfT[bb][2], sfT[bb][3]);
                pv.z = 0; pv.w = 0;
                const bf16x8 pf = __builtin_bit_cast(bf16x8, pv);
                #pragma unroll
                for (int db = 0; db < 4; db++) {
                    const bf16x4 v4 = *(const bf16x4*)
                        &Vs[(db * 16 + l16) * VS_STRIDE + (sub * 4 + bb) * 16 + quad * 4];
                    bf16x8 vf;
                    vf[0] = v4[0]; vf[1] = v4[1]; vf[2] = v4[2]; vf[3] = v4[3];
                    vf[4] = 0; vf[5] = 0; vf[6] = 0; vf[7] = 0;
                    o_acc[db] = __builtin_amdgcn_mfma_f32_16x16x32_bf16(
                        vf, pf, o_acc[db], 0, 0, 0);
                }
            }
        }
    }

    const size_t slab = ((size_t)h * NCH + kc) * S_LEN;

    if (quad == 0) {
        const int q = qw0 + l16;
        Mpart[slab + q] = m_i;
        Lpart[slab + q] = l_i;
    }

    // O^T -> LDS transpose (stride 72) -> coalesced store (128 rows x 64 d)
    __syncthreads();
    #pragma unroll
    for (int db = 0; db < 4; db++) {
        short4 pk4;
        pk4.x = f2bf(o_acc[db][0]); pk4.y = f2bf(o_acc[db][1]);
        pk4.z = f2bf(o_acc[db][2]); pk4.w = f2bf(o_acc[db][3]);
        *(short4*)&SMEM[(wave * 16 + l16) * 72 + db * 16 + quad * 4] = pk4;
    }
    __syncthreads();
    #pragma unroll
    for (int c = t; c < 1024; c += 512) {
        const int row = c >> 3, off = (c & 7) * 8;
        *(bf16x8*)&Opart[(slab + q0 + row) * DH + off] =
            *(const bf16x8*)&SMEM[row * 72 + off];
    }
}

// ---------------------------------------------------------------------------
// Kernel 2b: merge split-K partials -> Ctx bf16 [s][E].
// ---------------------------------------------------------------------------
template<int NCH, int CKL2>
__global__ __launch_bounds__(256) void flash_merge(
    const short* __restrict__ Opart, const float* __restrict__ Mpart,
    const float* __restrict__ Lpart, short* __restrict__ Ctx)
{
    const int row = blockIdx.x * 4 + (threadIdx.x >> 6);
    const int lane = threadIdx.x & 63;
    const int h = row >> 12, q = row & 4095;
    const int nc = (q >> CKL2) + 1;

    float mv[NCH], lv[NCH];
    float M = NEG_BIG;
    #pragma unroll
    for (int c = 0; c < NCH; c++) {
        if (c < nc) {
            mv[c] = Mpart[((size_t)h * NCH + c) * S_LEN + q];
            lv[c] = Lpart[((size_t)h * NCH + c) * S_LEN + q];
            M = fmaxf(M, mv[c]);
        }
    }
    float L = 0.f, O = 0.f;
    #pragma unroll
    for (int c = 0; c < NCH; c++) {
        if (c < nc) {
            const float w = __expf(mv[c] - M);
            L += w * lv[c];
            O += w * bf2f(Opart[(((size_t)h * NCH + c) * S_LEN + q) * DH + lane]);
        }
    }
    const float inv = (L > 0.f) ? 1.0f / L : 0.f;
    Ctx[(size_t)q * EMB + h * DH + lane] = f2bf(O * inv);
}

// ---------------------------------------------------------------------------
// Fallback single-pass flash (R3 version, proven) if ws_size too small.
// ---------------------------------------------------------------------------
__global__ __launch_bounds__(256) void flash_attn(
    const short* __restrict__ Qw, const short* __restrict__ Kw,
    const short* __restrict__ Vt, short* __restrict__ Ctx)
{
    __shared__ __align__(16) short Ks[128 * 64];
    __shared__ __align__(16) short Vs[64 * 128];
    __shared__ __align__(16) short Ps[4][32 * 128];

    const int h  = blockIdx.y;
    const int qt = (gridDim.x - 1) - blockIdx.x;
    const int q0 = qt * 128;
    const int t = threadIdx.x;
    const int lane = t & 63, wave = t >> 6;
    const int quad = lane >> 4, l16 = lane & 15;
    const int qw0 = q0 + wave * 32;

    bf16x8 qf[2][2];
    #pragma unroll
    for (int i = 0; i < 2; i++)
        #pragma unroll
        for (int kb = 0; kb < 2; kb++)
            qf[i][kb] = *(const bf16x8*)
                &Qw[((size_t)h * S_LEN + qw0 + i * 16 + l16) * DH + kb * 32 + quad * 8];

    float m_i[2][4], l_i[2][4];
    f32x4 o_acc[2][4] = {};
    #pragma unroll
    for (int i = 0; i < 2; i++)
        #pragma unroll
        for (int r = 0; r < 4; r++) { m_i[i][r] = NEG_BIG; l_i[i][r] = 0.f; }

    for (int kt = 0; kt <= qt; kt++) {
        const int k0 = kt * 128;
        __syncthreads();
        for (int c = t; c < 1024; c += 256) {
            const int row = c >> 3, cc = (c & 7) * 8;
            *(bf16x8*)&Ks[row * 64 + cc] =
                *(const bf16x8*)&Kw[((size_t)h * S_LEN + k0 + row) * DH + cc];
        }
        for (int c = t; c < 1024; c += 256) {
            const int row = c >> 4, cc = (c & 15) * 8;
            *(bf16x8*)&Vs[row * 128 + cc] =
                *(const bf16x8*)&Vt[((size_t)h * DH + row) * S_LEN + k0 + cc];
        }
        __syncthreads();

        f32x4 sf[2][8] = {};
        #pragma unroll
        for (int j = 0; j < 8; j++) {
            #pragma unroll
            for (int kb = 0; kb < 2; kb++) {
                const bf16x8 kf = *(const bf16x8*)
                    &Ks[(j * 16 + l16) * 64 + kb * 32 + quad * 8];
                #pragma unroll
                for (int i = 0; i < 2; i++)
                    sf[i][j] = __builtin_amdgcn_mfma_f32_16x16x32_bf16(
                        qf[i][kb], kf, sf[i][j], 0, 0, 0);
            }
        }

        const bool diag = (kt == qt);
        #pragma unroll
        for (int i = 0; i < 2; i++) {
            if (diag) {
                const int qbase = qw0 + i * 16 + quad * 4;
                const int kbase = k0 + l16;
                #pragma unroll
                for (int j = 0; j < 8; j++)
                    #pragma unroll
                    for (int r = 0; r < 4; r++)
                        if (kbase + j * 16 > qbase + r) sf[i][j][r] = NEG_BIG;
            }
            #pragma unroll
            for (int r = 0; r < 4; r++) {
                float mx = sf[i][0][r];
                #pragma unroll
                for (int j = 1; j < 8; j++) mx = fmaxf(mx, sf[i][j][r]);
                #pragma unroll
                for (int off = 1; off < 16; off <<= 1)
                    mx = fmaxf(mx, __shfl_xor(mx, off, 64));
                const float mnew = fmaxf(m_i[i][r], mx);
                const float alpha = __expf(m_i[i][r] - mnew);
                m_i[i][r] = mnew;
                float rs = 0.f;
                #pragma unroll
                for (int j = 0; j < 8; j++) {
                    const float p = __expf(sf[i][j][r] - mnew);
                    sf[i][j][r] = p;
                    rs += p;
                }
                #pragma unroll
                for (int off = 1; off < 16; off <<= 1)
                    rs += __shfl_xor(rs, off, 64);
                l_i[i][r] = l_i[i][r] * alpha + rs;
                #pragma unroll
                for (int db = 0; db < 4; db++) o_acc[i][db][r] *= alpha;
            }
            #pragma unroll
            for (int j = 0; j < 8; j++)
                #pragma unroll
                for (int r = 0; r < 4; r++)
                    Ps[wave][(i * 16 + quad * 4 + r) * 128 + j * 16 + l16] =
                        f2bf(sf[i][j][r]);
        }

        #pragma unroll
        for (int kb = 0; kb < 4; kb++) {
            bf16x8 pf[2];
            #pragma unroll
            for (int i = 0; i < 2; i++)
                pf[i] = *(const bf16x8*)
                    &Ps[wave][(i * 16 + l16) * 128 + kb * 32 + quad * 8];
            #pragma unroll
            for (int db = 0; db < 4; db++) {
                const bf16x8 vf = *(const bf16x8*)
                    &Vs[(db * 16 + l16) * 128 + kb * 32 + quad * 8];
                #pragma unroll
                for (int i = 0; i < 2; i++)
                    o_acc[i][db] = __builtin_amdgcn_mfma_f32_16x16x32_bf16(
                        pf[i], vf, o_acc[i][db], 0, 0, 0);
            }
        }
    }

    #pragma unroll
    for (int i = 0; i < 2; i++)
        #pragma unroll
        for (int r = 0; r < 4; r++) {
            const float li = l_i[i][r];
            const float inv = (li > 0.f) ? 1.0f / li : 0.f;
            const int m = qw0 + i * 16 + quad * 4 + r;
            #pragma unroll
            for (int db = 0; db < 4; db++) {
                const int d = db * 16 + l16;
                Ctx[(size_t)m * EMB + h * DH + d] = f2bf(o_acc[i][db][r] * inv);
            }
        }
}

// ---------------------------------------------------------------------------
// Kernel 3: output projection, bf16 inputs, global_load_lds staging.
// ---------------------------------------------------------------------------
__global__ __launch_bounds__(256) void out_gemm(
    const short* __restrict__ A, const short* __restrict__ Wb,
    const float* __restrict__ Bias, float* __restrict__ Out)
{
    __shared__ __align__(16) short As[128 * 64];
    __shared__ __align__(16) short Bs[128 * 64];

    const int m0 = blockIdx.x * 128;
    const int n0 = blockIdx.y * 128;
    const int t = threadIdx.x;
    const int lane = t & 63, wave = t >> 6;
    const int quad = lane >> 4, l16 = lane & 15;
    const int wm = (wave >> 1) * 64, wn = (wave & 1) * 64;
    const int srow = lane >> 3, scol = (lane & 7) * 8;

    f32x4 acc[4][4] = {};

    for (int k0 = 0; k0 < EMB; k0 += 64) {
        #pragma unroll
        for (int qd = 0; qd < 4; qd++) {
            const int chunk = wave * 4 + qd;
            const int row = chunk * 8 + srow;
            gld_lds16(&A [(size_t)(m0 + row) * EMB + k0 + scol], &As[chunk * 512]);
            gld_lds16(&Wb[(size_t)(n0 + row) * EMB + k0 + scol], &Bs[chunk * 512]);
        }
        __syncthreads();

        #pragma unroll
        for (int kb = 0; kb < 2; kb++) {
            bf16x8 af[4], bfr[4];
            #pragma unroll
            for (int i = 0; i < 4; i++)
                af[i] = *(const bf16x8*)&As[(wm + i * 16 + l16) * 64 + kb * 32 + quad * 8];
            #pragma unroll
            for (int j = 0; j < 4; j++)
                bfr[j] = *(const bf16x8*)&Bs[(wn + j * 16 + l16) * 64 + kb * 32 + quad * 8];
            #pragma unroll
            for (int i = 0; i < 4; i++)
                #pragma unroll
                for (int j = 0; j < 4; j++)
                    acc[i][j] = __builtin_amdgcn_mfma_f32_16x16x32_bf16(
                        af[i], bfr[j], acc[i][j], 0, 0, 0);
        }
        __syncthreads();
    }

    #pragma unroll
    for (int j = 0; j < 4; j++) {
        const int n = n0 + wn + j * 16 + l16;
        const float bias = Bias[n];
        #pragma unroll
        for (int i = 0; i < 4; i++)
            #pragma unroll
            for (int r = 0; r < 4; r++) {
                const int m = m0 + wm + i * 16 + quad * 4 + r;
                Out[(size_t)m * EMB + n] = acc[i][j][r] + bias;
            }
    }
}

// ---------------------------------------------------------------------------
extern "C" void kernel_launch(void* const* d_in, const int* in_sizes, int n_in,
                              void* d_out, int out_size, void* d_ws, size_t ws_size,
                              hipStream_t stream)
{
    (void)in_sizes; (void)n_in; (void)out_size;
    const float* x     = (const float*)d_in[0];
    const float* w_qkv = (const float*)d_in[2];
    const float* b_qkv = (const float*)d_in[3];
    const float* w_out = (const float*)d_in[4];
    const float* b_out = (const float*)d_in[5];
    float* out = (float*)d_out;

    char* ws = (char*)d_ws;
    const size_t SEG = (size_t)NH * S_LEN * DH * sizeof(short);     // 6 MB
    short* Qw  = (short*)(ws);
    short* Kw  = (short*)(ws + SEG);
    short* Vt  = (short*)(ws + 2 * SEG);
    short* Ctx = (short*)(ws + 3 * SEG);
    const size_t OP_OFF = 4 * SEG;

    auto op_sz = [&](int nch) { return (size_t)NH * nch * S_LEN * DH * sizeof(short); };
    auto ml_sz = [&](int nch) { return (size_t)NH * nch * S_LEN * sizeof(float); };
    const size_t need8 = OP_OFF + op_sz(8) + 2 * ml_sz(8);   // ~80 MB
    const size_t need4 = OP_OFF + op_sz(4) + 2 * ml_sz(4);   // ~51 MB

    const int XN8 = (S_LEN * EMB) / 8;
    const int WQ8 = (3 * EMB * EMB) / 8;
    const int WO8 = (EMB * EMB) / 8;
    const size_t WO_BYTES = (size_t)EMB * EMB * sizeof(short);
    short* Xb    = (short*)(ws + OP_OFF);
    short* Wqkvb = (short*)(ws + OP_OFF + (size_t)XN8 * 8 * sizeof(short));

    const int nch = (ws_size >= need8 + WO_BYTES) ? 8
                  : (ws_size >= need4)            ? 4 : 0;
    const size_t need = (nch == 8) ? need8 : need4;
    short* Opart = (short*)(ws + OP_OFF);
    float* Mpart = (float*)(ws + OP_OFF + op_sz(nch ? nch : 4));
    float* Lpart = (float*)(ws + OP_OFF + op_sz(nch ? nch : 4) + ml_sz(nch ? nch : 4));
    const bool big = ws_size >= need + WO_BYTES;
    short* Woutb = big ? (short*)(ws + need) : (short*)(ws + OP_OFF);

    if (big) {
        const int tot8 = XN8 + WQ8 + WO8;
        cvt3_bf16<<<dim3((tot8 + 255) / 256), 256, 0, stream>>>(
            x, Xb, XN8, w_qkv, Wqkvb, WQ8, w_out, Woutb, WO8);
    } else {
        cvt_bf16<<<dim3((XN8 + 255) / 256), 256, 0, stream>>>(x, Xb, XN8);
        cvt_bf16<<<dim3((WQ8 + 255) / 256), 256, 0, stream>>>(w_qkv, Wqkvb, WQ8);
    }

    qkv_gemm<<<dim3(S_LEN / 128, (3 * EMB) / 128), 256, 0, stream>>>(
        Xb, Wqkvb, b_qkv, Qw, Kw, Vt);

    if (nch == 8) {
        flash_partial<8, 9><<<dim3(S_LEN / 128, NH, 8), 512, 0, stream>>>(
            Qw, Kw, Vt, Opart, Mpart, Lpart);
        flash_merge<8, 9><<<dim3(NH * S_LEN / 4), 256, 0, stream>>>(
            Opart, Mpart, Lpart, Ctx);
    } else if (nch == 4) {
        flash_partial<4, 10><<<dim3(S_LEN / 128, NH, 4), 512, 0, stream>>>(
            Qw, Kw, Vt, Opart, Mpart, Lpart);
        flash_merge<4, 10><<<dim3(NH * S_LEN / 4), 256, 0, stream>>>(
            Opart, Mpart, Lpart, Ctx);
    } else {
        flash_attn<<<dim3(S_LEN / 128, NH), 256, 0, stream>>>(Qw, Kw, Vt, Ctx);
    }

    if (!big)
        cvt_bf16<<<dim3((WO8 + 255) / 256), 256, 0, stream>>>(w_out, Woutb, WO8);
    out_gemm<<<dim3(S_LEN / 128, EMB / 128), 256, 0, stream>>>(
        Ctx, Woutb, b_out, out);
}

// Round 15
// 285.157 us; speedup vs baseline: 1.0864x; 1.0864x over previous
//
#include <hip/hip_runtime.h>
#include <hip/hip_bf16.h>

#define S_LEN 4096
#define EMB   768
#define NH    12
#define DH    64
#define NCHUNK 4
#define CKL2   10         // chunk keys = 1024

#define KS_STRIDE 72      // padded (36 dwords % 32 = 4): breaks 16-way conflicts
#define VS_STRIDE 136     // padded (68 dwords % 32 = 4)

#define LOG2E 1.44269504088896f

// finite sentinel instead of -INFINITY: safe under fast-math builds
#define NEG_BIG (-1e30f)

// HW 2^x (v_exp_f32); __exp2f does not exist in HIP device code
#define EXP2F(x) __builtin_amdgcn_exp2f(x)

using bf16x8 = __attribute__((ext_vector_type(8))) short;
using bf16x4 = __attribute__((ext_vector_type(4))) short;
using f32x4  = __attribute__((ext_vector_type(4))) float;

__device__ __forceinline__ short f2bf(float f) {
    __hip_bfloat16 h = __float2bfloat16(f);
    short s; __builtin_memcpy(&s, &h, 2); return s;
}
__device__ __forceinline__ float bf2f(short s) {
    __hip_bfloat16 h; __builtin_memcpy(&h, &s, 2);
    return __bfloat162float(h);
}

// pack two f32 -> two bf16 (round-half-up) in one u32 via v_perm_b32
__device__ __forceinline__ unsigned pack_bf16_rh(float a, float b) {
    unsigned ua, ub;
    __builtin_memcpy(&ua, &a, 4);
    __builtin_memcpy(&ub, &b, 4);
    return __builtin_amdgcn_perm(ub + 0x8000u, ua + 0x8000u, 0x07060302u);
}

// async global->LDS, 16B per lane; lds dest = uniform base + lane*16
__device__ __forceinline__ void gld_lds16(const void* g, void* l) {
    __builtin_amdgcn_global_load_lds(
        (const __attribute__((address_space(1))) unsigned int*)g,
        (__attribute__((address_space(3))) unsigned int*)l, 16, 0, 0);
}

__device__ __forceinline__ void cvt8(const float* s, short* d, int i) {
    const float4 a = ((const float4*)s)[i * 2];
    const float4 b = ((const float4*)s)[i * 2 + 1];
    bf16x8 o;
    o[0] = f2bf(a.x); o[1] = f2bf(a.y); o[2] = f2bf(a.z); o[3] = f2bf(a.w);
    o[4] = f2bf(b.x); o[5] = f2bf(b.y); o[6] = f2bf(b.z); o[7] = f2bf(b.w);
    ((bf16x8*)d)[i] = o;
}

// ---------------------------------------------------------------------------
// Kernel 0a/0b: fp32 -> bf16 converts
// ---------------------------------------------------------------------------
__global__ __launch_bounds__(256) void cvt_bf16(
    const float* __restrict__ s, short* __restrict__ d, int n8)
{
    const int i = blockIdx.x * 256 + threadIdx.x;
    if (i < n8) cvt8(s, d, i);
}

__global__ __launch_bounds__(256) void cvt3_bf16(
    const float* __restrict__ x,  short* __restrict__ xb,  int n8x,
    const float* __restrict__ wq, short* __restrict__ wqb, int n8q,
    const float* __restrict__ wo, short* __restrict__ wob, int n8o)
{
    int i = blockIdx.x * 256 + threadIdx.x;
    if (i < n8x) { cvt8(x, xb, i); return; }
    i -= n8x;
    if (i < n8q) { cvt8(wq, wqb, i); return; }
    i -= n8q;
    if (i < n8o) cvt8(wo, wob, i);
}

// ---------------------------------------------------------------------------
// Kernel 1: QKV projection, bf16 inputs, global_load_lds staging.
// V-part tiles transpose C through LDS -> fully COALESCED Vt writes.
// R15 FIX: transpose write-out covers all 128 m-columns (was 64 -> half of
// Vt stayed poisoned; absmax 0.548 matched the half-zero-V signature).
// Q pre-scaled by log2(e) so flash uses exp2 (1 instr).
// ---------------------------------------------------------------------------
__global__ __launch_bounds__(256) void qkv_gemm(
    const short* __restrict__ Xb, const short* __restrict__ Wb,
    const float* __restrict__ Bias,
    short* __restrict__ Qw, short* __restrict__ Kw, short* __restrict__ Vt)
{
    __shared__ __align__(16) short SMEM[2 * 128 * 64];  // As | Bs ; reused as T
    short* As = SMEM;
    short* Bs = SMEM + 128 * 64;

    const int m0 = blockIdx.x * 128;
    const int n0 = blockIdx.y * 128;
    const int t = threadIdx.x;
    const int lane = t & 63, wave = t >> 6;
    const int quad = lane >> 4, l16 = lane & 15;
    const int wm = (wave >> 1) * 64, wn = (wave & 1) * 64;
    const int srow = lane >> 3, scol = (lane & 7) * 8;

    f32x4 acc[4][4] = {};

    for (int k0 = 0; k0 < EMB; k0 += 64) {
        #pragma unroll
        for (int qd = 0; qd < 4; qd++) {
            const int chunk = wave * 4 + qd;
            const int row = chunk * 8 + srow;
            gld_lds16(&Xb[(size_t)(m0 + row) * EMB + k0 + scol], &As[chunk * 512]);
            gld_lds16(&Wb[(size_t)(n0 + row) * EMB + k0 + scol], &Bs[chunk * 512]);
        }
        __syncthreads();

        #pragma unroll
        for (int kb = 0; kb < 2; kb++) {
            bf16x8 af[4], bfr[4];
            #pragma unroll
            for (int i = 0; i < 4; i++)
                af[i] = *(const bf16x8*)&As[(wm + i * 16 + l16) * 64 + kb * 32 + quad * 8];
            #pragma unroll
            for (int j = 0; j < 4; j++)
                bfr[j] = *(const bf16x8*)&Bs[(wn + j * 16 + l16) * 64 + kb * 32 + quad * 8];
            #pragma unroll
            for (int i = 0; i < 4; i++)
                #pragma unroll
                for (int j = 0; j < 4; j++)
                    acc[i][j] = __builtin_amdgcn_mfma_f32_16x16x32_bf16(
                        af[i], bfr[j], acc[i][j], 0, 0, 0);
        }
        __syncthreads();
    }

    const int part = n0 / EMB;           // block-uniform: 0=Q 1=K 2=V

    if (part < 2) {
        // Q/K: Q scaled by log2e for exp2-domain softmax.
        const float qs = (part == 0) ? LOG2E : 1.0f;
        #pragma unroll
        for (int j = 0; j < 4; j++) {
            const int n = n0 + wn + j * 16 + l16;
            const float bias = Bias[n];
            const int r768 = n % EMB;
            const int h = r768 >> 6, d = r768 & 63;
            short* dst = (part == 0) ? Qw : Kw;
            #pragma unroll
            for (int i = 0; i < 4; i++)
                #pragma unroll
                for (int r = 0; r < 4; r++) {
                    const int m = m0 + wm + i * 16 + quad * 4 + r;
                    dst[((size_t)h * S_LEN + m) * DH + d] =
                        f2bf((acc[i][j][r] + bias) * qs);
                }
        }
    } else {
        // V: transpose C-tile through LDS T[128 n][128 m], coalesced Vt rows.
        #pragma unroll
        for (int j = 0; j < 4; j++) {
            const int nl = wn + j * 16 + l16;
            const float bias = Bias[n0 + nl];
            #pragma unroll
            for (int i = 0; i < 4; i++) {
                short4 v;
                v.x = f2bf(acc[i][j][0] + bias);
                v.y = f2bf(acc[i][j][1] + bias);
                v.z = f2bf(acc[i][j][2] + bias);
                v.w = f2bf(acc[i][j][3] + bias);
                *(short4*)&SMEM[nl * 128 + wm + i * 16 + quad * 4] = v;
            }
        }
        __syncthreads();
        const int vrow0 = n0 - 2 * EMB;          // Vt row base = h*64+d = r768
        #pragma unroll
        for (int c = t; c < 2048; c += 256) {    // 2048 chunks = 128 rows x 128 m
            const int row = c >> 4, off = (c & 15) * 8;
            *(bf16x8*)&Vt[(size_t)(vrow0 + row) * S_LEN + m0 + off] =
                *(const bf16x8*)&SMEM[row * 128 + off];
        }
    }
}

// ---------------------------------------------------------------------------
// Kernel 2a: split-K flash partial (256 thr, q-tile 64, nch=4),
// exp2-domain softmax (Q pre-scaled by log2e).
// ---------------------------------------------------------------------------
__global__ __launch_bounds__(256) void flash_partial(
    const short* __restrict__ Qw, const short* __restrict__ Kw,
    const short* __restrict__ Vt,
    short* __restrict__ Opart, float* __restrict__ Mpart,
    float* __restrict__ Lpart)
{
    const int qt = blockIdx.x;          // 64-row q tile
    const int h  = blockIdx.y;
    const int kc = blockIdx.z;
    const int q0  = qt * 64;
    const int ks0 = kc << CKL2;
    if (ks0 > q0) return;
    const int KIT = (1 << CKL2) / 128;
    const int T  = q0 >> 7;
    const int nk = min(KIT, T - KIT * kc + 1);

    __shared__ __align__(16) short SMEM[128 * KS_STRIDE + 64 * VS_STRIDE]; // 35 KB
    short* Ks = SMEM;
    short* Vs = SMEM + 128 * KS_STRIDE;

    const int t = threadIdx.x;
    const int lane = t & 63, wave = t >> 6;
    const int quad = lane >> 4, l16 = lane & 15;
    const int qw0 = q0 + wave * 16;

    bf16x8 qf[2];
    #pragma unroll
    for (int kb = 0; kb < 2; kb++)
        qf[kb] = *(const bf16x8*)
            &Qw[((size_t)h * S_LEN + qw0 + l16) * DH + kb * 32 + quad * 8];

    float m_i = NEG_BIG, l_i = 0.f;
    f32x4 o_acc[4] = {};

    for (int kt = 0; kt < nk; kt++) {
        const int k0 = ks0 + kt * 128;
        __syncthreads();
        #pragma unroll
        for (int c = t; c < 1024; c += 256) {
            const int row = c >> 3, cc = (c & 7) * 8;
            *(bf16x8*)&Ks[row * KS_STRIDE + cc] =
                *(const bf16x8*)&Kw[((size_t)h * S_LEN + k0 + row) * DH + cc];
        }
        #pragma unroll
        for (int c = t; c < 1024; c += 256) {
            const int row = c >> 4, cc = (c & 15) * 8;
            *(bf16x8*)&Vs[row * VS_STRIDE + cc] =
                *(const bf16x8*)&Vt[((size_t)h * DH + row) * S_LEN + k0 + cc];
        }
        __syncthreads();

        const bool maskn = (k0 + 127 > q0);
        #pragma unroll
        for (int sub = 0; sub < 2; sub++) {
            if (maskn && k0 + sub * 64 > qw0 + 15) continue;

            f32x4 sfT[4] = {};
            #pragma unroll
            for (int bb = 0; bb < 4; bb++) {
                #pragma unroll
                for (int kb = 0; kb < 2; kb++) {
                    const bf16x8 kf = *(const bf16x8*)
                        &Ks[((sub * 4 + bb) * 16 + l16) * KS_STRIDE + kb * 32 + quad * 8];
                    sfT[bb] = __builtin_amdgcn_mfma_f32_16x16x32_bf16(
                        kf, qf[kb], sfT[bb], 0, 0, 0);
                }
            }

            const int qg = qw0 + l16;
            if (maskn) {
                #pragma unroll
                for (int bb = 0; bb < 4; bb++)
                    #pragma unroll
                    for (int r = 0; r < 4; r++)
                        if (k0 + (sub * 4 + bb) * 16 + quad * 4 + r > qg)
                            sfT[bb][r] = NEG_BIG;
            }
            float mx = sfT[0][0];
            #pragma unroll
            for (int bb = 0; bb < 4; bb++)
                #pragma unroll
                for (int r = 0; r < 4; r++) mx = fmaxf(mx, sfT[bb][r]);
            mx = fmaxf(mx, __shfl_xor(mx, 16, 64));
            mx = fmaxf(mx, __shfl_xor(mx, 32, 64));
            const float mnew = fmaxf(m_i, mx);
            const float alpha = EXP2F(m_i - mnew);    // log2-domain
            m_i = mnew;
            float rs = 0.f;
            #pragma unroll
            for (int bb = 0; bb < 4; bb++)
                #pragma unroll
                for (int r = 0; r < 4; r++) {
                    const float p = EXP2F(sfT[bb][r] - mnew);
                    sfT[bb][r] = p;
                    rs += p;
                }
            rs += __shfl_xor(rs, 16, 64);
            rs += __shfl_xor(rs, 32, 64);
            l_i = l_i * alpha + rs;
            #pragma unroll
            for (int db = 0; db < 4; db++) o_acc[db] *= alpha;

            #pragma unroll
            for (int bb = 0; bb < 4; bb++) {
                int4 pv;
                pv.x = (int)pack_bf16_rh(sfT[bb][0], sfT[bb][1]);
                pv.y = (int)pack_bf16_rh(sfT[bb][2], sfT[bb][3]);
                pv.z = 0; pv.w = 0;
                const bf16x8 pf = __builtin_bit_cast(bf16x8, pv);
                #pragma unroll
                for (int db = 0; db < 4; db++) {
                    const bf16x4 v4 = *(const bf16x4*)
                        &Vs[(db * 16 + l16) * VS_STRIDE + (sub * 4 + bb) * 16 + quad * 4];
                    bf16x8 vf;
                    vf[0] = v4[0]; vf[1] = v4[1]; vf[2] = v4[2]; vf[3] = v4[3];
                    vf[4] = 0; vf[5] = 0; vf[6] = 0; vf[7] = 0;
                    o_acc[db] = __builtin_amdgcn_mfma_f32_16x16x32_bf16(
                        vf, pf, o_acc[db], 0, 0, 0);
                }
            }
        }
    }

    const size_t slab = ((size_t)h * NCHUNK + kc) * S_LEN;

    if (quad == 0) {
        const int q = qw0 + l16;
        Mpart[slab + q] = m_i;
        Lpart[slab + q] = l_i;
    }

    __syncthreads();
    #pragma unroll
    for (int db = 0; db < 4; db++) {
        short4 pk4;
        pk4.x = f2bf(o_acc[db][0]); pk4.y = f2bf(o_acc[db][1]);
        pk4.z = f2bf(o_acc[db][2]); pk4.w = f2bf(o_acc[db][3]);
        *(short4*)&SMEM[(wave * 16 + l16) * 72 + db * 16 + quad * 4] = pk4;
    }
    __syncthreads();
    #pragma unroll
    for (int c = t; c < 512; c += 256) {
        const int row = c >> 3, off = (c & 7) * 8;
        *(bf16x8*)&Opart[(slab + q0 + row) * DH + off] =
            *(const bf16x8*)&SMEM[row * 72 + off];
    }
}

// ---------------------------------------------------------------------------
// Kernel 2b: merge split-K partials -> Ctx bf16 [s][E]. (exp2-domain)
// ---------------------------------------------------------------------------
__global__ __launch_bounds__(256) void flash_merge(
    const short* __restrict__ Opart, const float* __restrict__ Mpart,
    const float* __restrict__ Lpart, short* __restrict__ Ctx)
{
    const int row = blockIdx.x * 4 + (threadIdx.x >> 6);
    const int lane = threadIdx.x & 63;
    const int h = row >> 12, q = row & 4095;
    const int nc = (q >> CKL2) + 1;

    float mv[NCHUNK], lv[NCHUNK];
    float M = NEG_BIG;
    #pragma unroll
    for (int c = 0; c < NCHUNK; c++) {
        if (c < nc) {
            mv[c] = Mpart[((size_t)h * NCHUNK + c) * S_LEN + q];
            lv[c] = Lpart[((size_t)h * NCHUNK + c) * S_LEN + q];
            M = fmaxf(M, mv[c]);
        }
    }
    float L = 0.f, O = 0.f;
    #pragma unroll
    for (int c = 0; c < NCHUNK; c++) {
        if (c < nc) {
            const float w = EXP2F(mv[c] - M);
            L += w * lv[c];
            O += w * bf2f(Opart[(((size_t)h * NCHUNK + c) * S_LEN + q) * DH + lane]);
        }
    }
    const float inv = (L > 0.f) ? 1.0f / L : 0.f;
    Ctx[(size_t)q * EMB + h * DH + lane] = f2bf(O * inv);
}

// ---------------------------------------------------------------------------
// Fallback single-pass flash (exp2-domain, Q pre-scaled) if ws too small.
// ---------------------------------------------------------------------------
__global__ __launch_bounds__(256) void flash_attn(
    const short* __restrict__ Qw, const short* __restrict__ Kw,
    const short* __restrict__ Vt, short* __restrict__ Ctx)
{
    __shared__ __align__(16) short Ks[128 * 64];
    __shared__ __align__(16) short Vs[64 * 128];
    __shared__ __align__(16) short Ps[4][32 * 128];

    const int h  = blockIdx.y;
    const int qt = (gridDim.x - 1) - blockIdx.x;
    const int q0 = qt * 128;
    const int t = threadIdx.x;
    const int lane = t & 63, wave = t >> 6;
    const int quad = lane >> 4, l16 = lane & 15;
    const int qw0 = q0 + wave * 32;

    bf16x8 qf[2][2];
    #pragma unroll
    for (int i = 0; i < 2; i++)
        #pragma unroll
        for (int kb = 0; kb < 2; kb++)
            qf[i][kb] = *(const bf16x8*)
                &Qw[((size_t)h * S_LEN + qw0 + i * 16 + l16) * DH + kb * 32 + quad * 8];

    float m_i[2][4], l_i[2][4];
    f32x4 o_acc[2][4] = {};
    #pragma unroll
    for (int i = 0; i < 2; i++)
        #pragma unroll
        for (int r = 0; r < 4; r++) { m_i[i][r] = NEG_BIG; l_i[i][r] = 0.f; }

    for (int kt = 0; kt <= qt; kt++) {
        const int k0 = kt * 128;
        __syncthreads();
        for (int c = t; c < 1024; c += 256) {
            const int row = c >> 3, cc = (c & 7) * 8;
            *(bf16x8*)&Ks[row * 64 + cc] =
                *(const bf16x8*)&Kw[((size_t)h * S_LEN + k0 + row) * DH + cc];
        }
        for (int c = t; c < 1024; c += 256) {
            const int row = c >> 4, cc = (c & 15) * 8;
            *(bf16x8*)&Vs[row * 128 + cc] =
                *(const bf16x8*)&Vt[((size_t)h * DH + row) * S_LEN + k0 + cc];
        }
        __syncthreads();

        f32x4 sf[2][8] = {};
        #pragma unroll
        for (int j = 0; j < 8; j++) {
            #pragma unroll
            for (int kb = 0; kb < 2; kb++) {
                const bf16x8 kf = *(const bf16x8*)
                    &Ks[(j * 16 + l16) * 64 + kb * 32 + quad * 8];
                #pragma unroll
                for (int i = 0; i < 2; i++)
                    sf[i][j] = __builtin_amdgcn_mfma_f32_16x16x32_bf16(
                        qf[i][kb], kf, sf[i][j], 0, 0, 0);
            }
        }

        const bool diag = (kt == qt);
        #pragma unroll
        for (int i = 0; i < 2; i++) {
            if (diag) {
                const int qbase = qw0 + i * 16 + quad * 4;
                const int kbase = k0 + l16;
                #pragma unroll
                for (int j = 0; j < 8; j++)
                    #pragma unroll
                    for (int r = 0; r < 4; r++)
                        if (kbase + j * 16 > qbase + r) sf[i][j][r] = NEG_BIG;
            }
            #pragma unroll
            for (int r = 0; r < 4; r++) {
                float mx = sf[i][0][r];
                #pragma unroll
                for (int j = 1; j < 8; j++) mx = fmaxf(mx, sf[i][j][r]);
                #pragma unroll
                for (int off = 1; off < 16; off <<= 1)
                    mx = fmaxf(mx, __shfl_xor(mx, off, 64));
                const float mnew = fmaxf(m_i[i][r], mx);
                const float alpha = EXP2F(m_i[i][r] - mnew);
                m_i[i][r] = mnew;
                float rs = 0.f;
                #pragma unroll
                for (int j = 0; j < 8; j++) {
                    const float p = EXP2F(sf[i][j][r] - mnew);
                    sf[i][j][r] = p;
                    rs += p;
                }
                #pragma unroll
                for (int off = 1; off < 16; off <<= 1)
                    rs += __shfl_xor(rs, off, 64);
                l_i[i][r] = l_i[i][r] * alpha + rs;
                #pragma unroll
                for (int db = 0; db < 4; db++) o_acc[i][db][r] *= alpha;
            }
            #pragma unroll
            for (int j = 0; j < 8; j++)
                #pragma unroll
                for (int r = 0; r < 4; r++)
                    Ps[wave][(i * 16 + quad * 4 + r) * 128 + j * 16 + l16] =
                        f2bf(sf[i][j][r]);
        }

        #pragma unroll
        for (int kb = 0; kb < 4; kb++) {
            bf16x8 pf[2];
            #pragma unroll
            for (int i = 0; i < 2; i++)
                pf[i] = *(const bf16x8*)
                    &Ps[wave][(i * 16 + l16) * 128 + kb * 32 + quad * 8];
            #pragma unroll
            for (int db = 0; db < 4; db++) {
                const bf16x8 vf = *(const bf16x8*)
                    &Vs[(db * 16 + l16) * 128 + kb * 32 + quad * 8];
                #pragma unroll
                for (int i = 0; i < 2; i++)
                    o_acc[i][db] = __builtin_amdgcn_mfma_f32_16x16x32_bf16(
                        pf[i], vf, o_acc[i][db], 0, 0, 0);
            }
        }
    }

    #pragma unroll
    for (int i = 0; i < 2; i++)
        #pragma unroll
        for (int r = 0; r < 4; r++) {
            const float li = l_i[i][r];
            const float inv = (li > 0.f) ? 1.0f / li : 0.f;
            const int m = qw0 + i * 16 + quad * 4 + r;
            #pragma unroll
            for (int db = 0; db < 4; db++) {
                const int d = db * 16 + l16;
                Ctx[(size_t)m * EMB + h * DH + d] = f2bf(o_acc[i][db][r] * inv);
            }
        }
}

// ---------------------------------------------------------------------------
// Kernel 3: output projection, bf16 inputs, global_load_lds staging.
// ---------------------------------------------------------------------------
__global__ __launch_bounds__(256) void out_gemm(
    const short* __restrict__ A, const short* __restrict__ Wb,
    const float* __restrict__ Bias, float* __restrict__ Out)
{
    __shared__ __align__(16) short As[128 * 64];
    __shared__ __align__(16) short Bs[128 * 64];

    const int m0 = blockIdx.x * 128;
    const int n0 = blockIdx.y * 128;
    const int t = threadIdx.x;
    const int lane = t & 63, wave = t >> 6;
    const int quad = lane >> 4, l16 = lane & 15;
    const int wm = (wave >> 1) * 64, wn = (wave & 1) * 64;
    const int srow = lane >> 3, scol = (lane & 7) * 8;

    f32x4 acc[4][4] = {};

    for (int k0 = 0; k0 < EMB; k0 += 64) {
        #pragma unroll
        for (int qd = 0; qd < 4; qd++) {
            const int chunk = wave * 4 + qd;
            const int row = chunk * 8 + srow;
            gld_lds16(&A [(size_t)(m0 + row) * EMB + k0 + scol], &As[chunk * 512]);
            gld_lds16(&Wb[(size_t)(n0 + row) * EMB + k0 + scol], &Bs[chunk * 512]);
        }
        __syncthreads();

        #pragma unroll
        for (int kb = 0; kb < 2; kb++) {
            bf16x8 af[4], bfr[4];
            #pragma unroll
            for (int i = 0; i < 4; i++)
                af[i] = *(const bf16x8*)&As[(wm + i * 16 + l16) * 64 + kb * 32 + quad * 8];
            #pragma unroll
            for (int j = 0; j < 4; j++)
                bfr[j] = *(const bf16x8*)&Bs[(wn + j * 16 + l16) * 64 + kb * 32 + quad * 8];
            #pragma unroll
            for (int i = 0; i < 4; i++)
                #pragma unroll
                for (int j = 0; j < 4; j++)
                    acc[i][j] = __builtin_amdgcn_mfma_f32_16x16x32_bf16(
                        af[i], bfr[j], acc[i][j], 0, 0, 0);
        }
        __syncthreads();
    }

    #pragma unroll
    for (int j = 0; j < 4; j++) {
        const int n = n0 + wn + j * 16 + l16;
        const float bias = Bias[n];
        #pragma unroll
        for (int i = 0; i < 4; i++)
            #pragma unroll
            for (int r = 0; r < 4; r++) {
                const int m = m0 + wm + i * 16 + quad * 4 + r;
                Out[(size_t)m * EMB + n] = acc[i][j][r] + bias;
            }
    }
}

// ---------------------------------------------------------------------------
extern "C" void kernel_launch(void* const* d_in, const int* in_sizes, int n_in,
                              void* d_out, int out_size, void* d_ws, size_t ws_size,
                              hipStream_t stream)
{
    (void)in_sizes; (void)n_in; (void)out_size;
    const float* x     = (const float*)d_in[0];
    const float* w_qkv = (const float*)d_in[2];
    const float* b_qkv = (const float*)d_in[3];
    const float* w_out = (const float*)d_in[4];
    const float* b_out = (const float*)d_in[5];
    float* out = (float*)d_out;

    char* ws = (char*)d_ws;
    const size_t SEG = (size_t)NH * S_LEN * DH * sizeof(short);     // 6 MB
    short* Qw  = (short*)(ws);
    short* Kw  = (short*)(ws + SEG);
    short* Vt  = (short*)(ws + 2 * SEG);
    short* Ctx = (short*)(ws + 3 * SEG);
    const size_t OP_OFF = 4 * SEG;
    const size_t OP_SZ  = (size_t)NH * NCHUNK * S_LEN * DH * sizeof(short);
    const size_t ML_SZ  = (size_t)NH * NCHUNK * S_LEN * sizeof(float);
    short* Opart = (short*)(ws + OP_OFF);
    float* Mpart = (float*)(ws + OP_OFF + OP_SZ);
    float* Lpart = (float*)(ws + OP_OFF + OP_SZ + ML_SZ);
    const size_t need = OP_OFF + OP_SZ + 2 * ML_SZ;

    const int XN8 = (S_LEN * EMB) / 8;
    const int WQ8 = (3 * EMB * EMB) / 8;
    const int WO8 = (EMB * EMB) / 8;
    const size_t WO_BYTES = (size_t)EMB * EMB * sizeof(short);
    short* Xb    = (short*)(ws + OP_OFF);
    short* Wqkvb = (short*)(ws + OP_OFF + (size_t)XN8 * 8 * sizeof(short));
    const bool big = ws_size >= need + WO_BYTES;
    short* Woutb = big ? (short*)(ws + need) : (short*)(ws + OP_OFF);

    if (big) {
        const int tot8 = XN8 + WQ8 + WO8;
        cvt3_bf16<<<dim3((tot8 + 255) / 256), 256, 0, stream>>>(
            x, Xb, XN8, w_qkv, Wqkvb, WQ8, w_out, Woutb, WO8);
    } else {
        cvt_bf16<<<dim3((XN8 + 255) / 256), 256, 0, stream>>>(x, Xb, XN8);
        cvt_bf16<<<dim3((WQ8 + 255) / 256), 256, 0, stream>>>(w_qkv, Wqkvb, WQ8);
    }

    qkv_gemm<<<dim3(S_LEN / 128, (3 * EMB) / 128), 256, 0, stream>>>(
        Xb, Wqkvb, b_qkv, Qw, Kw, Vt);

    if (ws_size >= need) {
        flash_partial<<<dim3(S_LEN / 64, NH, NCHUNK), 256, 0, stream>>>(
            Qw, Kw, Vt, Opart, Mpart, Lpart);
        flash_merge<<<dim3(NH * S_LEN / 4), 256, 0, stream>>>(
            Opart, Mpart, Lpart, Ctx);
    } else {
        flash_attn<<<dim3(S_LEN / 128, NH), 256, 0, stream>>>(Qw, Kw, Vt, Ctx);
    }

    if (!big)
        cvt_bf16<<<dim3((WO8 + 255) / 256), 256, 0, stream>>>(w_out, Woutb, WO8);
    out_gemm<<<dim3(S_LEN / 128, EMB / 128), 256, 0, stream>>>(
        Ctx, Woutb, b_out, out);
}